// Round 14
// baseline (3423.539 us; speedup 1.0000x reference)
//
#include <hip/hip_runtime.h>

// ---------------------------------------------------------------------------
// Persistent 2-layer LSTM, MI355X. Round 25 = Round-24 base (3269 us, best) +
// BOUNDED TAIL-RETRY on the early-poll.
// r24 post-mortem: tail early-poll = -5% (prediction matched) — taking the
// poll RT off the head pays when the tail check HITS. Misses are structural:
// L0 checks immediately after its own publish, while peers' agent-scope flag
// stores take ~600cy to become visible; L1 checks ~500cy after publish.
// This round: the tail check retries up to 3x with s_sleep(2) (~128cy)
// between attempts. Tail-retry time substitutes 1:1 for head-wait time
// (waves 1-3 idle at the barrier either way; a failed last retry falls
// through to the unchanged head wait), so each converted miss saves a full
// poll RT (~600-900cy). Only +<=2 poll loads/step/WG of extra traffic.
// Everything else r24 verbatim: XCD-verified L2 data path (plain stores +
// sc0 loads), agent-scope flags ALWAYS (r19/r21: fast flags hang, 2/2),
// private 16B flag slots, branchless afrag, merged L1 wait+dual-stage,
// EWMA predictive sleep, wave-0-only polling, 16+16 WGs/group, weights in
// VGPRs, h0 depth-4 / h1 depth-2 planes, 1 WG/CU pad.
// Pre-commit: neutral (+-2%) => early-poll near-always hits; remaining
// period = stage RT + MFMA/LDS bandwidth + barriers + intrinsic max-of-16
// straggler => declare ROOFLINE next round.
// ---------------------------------------------------------------------------

#define T_STEPS 1024
#define WS_FLAG_OFF 0                     // 8 groups * 512 B: 32 pubs x 16 B each
#define WS_H0_OFF  4096                   // [8 g][4 depth][16 wg][8 b][32 u] f16
#define WS_H1_OFF  (4096 + 8*4*8192)      // [8 g][2 depth][...]
#define WS_NEED    (WS_H1_OFF + 8*2*8192) // 397312 B (r20 known-good size)

#define SCOPE __HIP_MEMORY_SCOPE_AGENT

typedef _Float16 f16;
typedef _Float16 f16x8 __attribute__((ext_vector_type(8)));
typedef float    f32x4 __attribute__((ext_vector_type(4)));
typedef unsigned long long u64;

#define HP_STRIDE 520   // padded LDS plane row stride (f16)

__device__ __forceinline__ float sigm_(float x) {
    x = fminf(fmaxf(x, -30.f), 30.f);
    return 1.f / (1.f + __expf(-x));
}
__device__ __forceinline__ float tanh_(float x) {
    x = fminf(fmaxf(x, -15.f), 15.f);
    float e = __expf(-2.f * x);
    return (1.f - e) / (1.f + e);
}

// A-fragment for 16x16x32 f16 MFMA from a padded LDS plane — BRANCHLESS
// (r18): lanes 8-15 re-read rows 0-7; their D rows are discarded by the q<2
// store guard.
__device__ __forceinline__ f16x8 afrag_lds(const f16* __restrict__ hp, int kbase,
                                           int b, int q) {
    return *(const f16x8*)(hp + (b & 7) * HP_STRIDE + kbase + q * 8);
}

__device__ __forceinline__ f16x8 pack8(const float* p) {
    float4 a = *(const float4*)p, b = *(const float4*)(p + 4);
    f16x8 f;
    f[0] = (f16)a.x; f[1] = (f16)a.y; f[2] = (f16)a.z; f[3] = (f16)a.w;
    f[4] = (f16)b.x; f[5] = (f16)b.y; f[6] = (f16)b.z; f[7] = (f16)b.w;
    return f;
}

// One-shot NON-BLOCKING flag check (wave0 only; lanes 0-15 flag0, 16-31
// flag1, 32-63 INT_MAX). Flags are monotone, so a pass observed in the tail
// remains valid at the next head.
__device__ __forceinline__ bool check_flags(const int* f0, int t0,
                                            const int* f1, int t1, int lane) {
    const int* p = (lane & 16) ? (f1 + (lane & 15) * 4) : (f0 + (lane & 15) * 4);
    const int tgt = (lane & 16) ? t1 : t0;
    const bool act = (lane < 32);
    int v = act ? __hip_atomic_load(p, __ATOMIC_RELAXED, SCOPE) : 0x7fffffff;
    return __all(v >= tgt);
}

// Bounded tail retry: up to 3 attempts, s_sleep(2) between. Time spent here
// substitutes 1:1 for head-wait time; a failed last attempt falls through to
// the unchanged head wait.
__device__ __forceinline__ bool check_flags_retry(const int* f0, int t0,
                                                  const int* f1, int t1,
                                                  int lane) {
    if (check_flags(f0, t0, f1, t1, lane)) return true;
    __builtin_amdgcn_s_sleep(2);
    if (check_flags(f0, t0, f1, t1, lane)) return true;
    __builtin_amdgcn_s_sleep(2);
    return check_flags(f0, t0, f1, t1, lane);
}

// Blocking wait (r15/r18): EWMA predictive coarse sleep then fine-poll.
// ALWAYS agent-scope (r19/r21 lesson: fast flags hang, 2/2).
__device__ __forceinline__ long long wait_flags(const int* f0, int t0,
                                                const int* f1, int t1, int lane,
                                                long long predict_clk) {
    const int* p = (lane & 16) ? (f1 + (lane & 15) * 4) : (f0 + (lane & 15) * 4);
    const int tgt = (lane & 16) ? t1 : t0;
    const bool act = (lane < 32);
    int v = act ? __hip_atomic_load(p, __ATOMIC_RELAXED, SCOPE) : 0x7fffffff;
    if (__all(v >= tgt)) return 0;                 // fast path: no wait
    long long t0c = (long long)__builtin_amdgcn_s_memtime();
    int rep = (int)(predict_clk >> 12);            // ~half wait / ~2000cy burst
    if (rep > 8) rep = 8;
    for (int i = 0; i < rep; ++i) __builtin_amdgcn_s_sleep(31);
    int spins = 0;
    for (;;) {
        v = act ? __hip_atomic_load(p, __ATOMIC_RELAXED, SCOPE) : 0x7fffffff;
        if (__all(v >= tgt)) break;
        ++spins;
        if (spins < 32)       __builtin_amdgcn_s_sleep(1);
        else if (spins < 256) __builtin_amdgcn_s_sleep(4);
        else                  __builtin_amdgcn_s_sleep(16);
        if (spins > (1 << 20)) break;   // anti-hang safety valve
    }
    return (long long)__builtin_amdgcn_s_memtime() - t0c;
}

// EWMA update: decay toward the new sample (or toward 0 on fast path).
__device__ __forceinline__ long long ewma_upd(long long ew, long long d) {
    return ew - (ew >> 2) + (d >> 2);
}

// sc0 (L1-bypass, L2-served) u64 load for the XCD-local fast path.
__device__ __forceinline__ u64 ld8_sc0(const u64* p) {
    u64 v;
    asm volatile("global_load_dwordx2 %0, %1, off sc0" : "=v"(v) : "v"(p));
    return v;
}

// Stage one 8 KB h-plane into the padded LDS plane.
__device__ __forceinline__ void stage_plane(const f16* __restrict__ gp,
                                            f16* __restrict__ dst, int tid,
                                            bool fast) {
    const u64* g8 = (const u64*)gp;
    u64 v[4];
    if (fast) {
#pragma unroll
        for (int jj = 0; jj < 4; ++jj) v[jj] = ld8_sc0(g8 + jj * 256 + tid);
        asm volatile("s_waitcnt vmcnt(0)" ::: "memory");
    } else {
#pragma unroll
        for (int jj = 0; jj < 4; ++jj)
            v[jj] = __hip_atomic_load(g8 + jj * 256 + tid, __ATOMIC_RELAXED, SCOPE);
    }
#pragma unroll
    for (int jj = 0; jj < 4; ++jj) {
        int i = jj * 256 + tid;
        int wg = i >> 6, b = (i >> 3) & 7, j = i & 7;
        *(u64*)(dst + b * HP_STRIDE + wg * 32 + j * 4) = v[jj];
    }
}

// Stage TWO 8 KB h-planes in one pass (one RT on the serial chain, r13).
__device__ __forceinline__ void stage_two(const f16* __restrict__ gpA,
                                          f16* __restrict__ dstA,
                                          const f16* __restrict__ gpB,
                                          f16* __restrict__ dstB, int tid,
                                          bool fast) {
    const u64* ga = (const u64*)gpA;
    const u64* gb = (const u64*)gpB;
    u64 va[4], vb[4];
    if (fast) {
#pragma unroll
        for (int jj = 0; jj < 4; ++jj) va[jj] = ld8_sc0(ga + jj * 256 + tid);
#pragma unroll
        for (int jj = 0; jj < 4; ++jj) vb[jj] = ld8_sc0(gb + jj * 256 + tid);
        asm volatile("s_waitcnt vmcnt(0)" ::: "memory");
    } else {
#pragma unroll
        for (int jj = 0; jj < 4; ++jj)
            va[jj] = __hip_atomic_load(ga + jj * 256 + tid, __ATOMIC_RELAXED, SCOPE);
#pragma unroll
        for (int jj = 0; jj < 4; ++jj)
            vb[jj] = __hip_atomic_load(gb + jj * 256 + tid, __ATOMIC_RELAXED, SCOPE);
    }
#pragma unroll
    for (int jj = 0; jj < 4; ++jj) {
        int i = jj * 256 + tid;
        int wg = i >> 6, b = (i >> 3) & 7, j = i & 7;
        *(u64*)(dstA + b * HP_STRIDE + wg * 32 + j * 4) = va[jj];
        *(u64*)(dstB + b * HP_STRIDE + wg * 32 + j * 4) = vb[jj];
    }
}

// x A-fragment for step t.
__device__ __forceinline__ f16x8 load_xfrag(const float* __restrict__ x,
                                            int gb8, int t, int ln, int q) {
    f16x8 f = {(_Float16)0, (_Float16)0, (_Float16)0, (_Float16)0,
               (_Float16)0, (_Float16)0, (_Float16)0, (_Float16)0};
    if (ln < 8 && t < T_STEPS) {
        const float* xp = x + ((size_t)(gb8 + ln) * 1024 + t) * 21;
#pragma unroll
        for (int j = 0; j < 8; ++j) {
            int kl = q * 8 + j;
            if (kl < 21) f[j] = (f16)xp[kl];
        }
    }
    return f;
}

// Zeros visible everywhere: agent-scope stores invalidate stale dirty L2
// lines (r20-proven across 68 dispatches) and land in the LLC.
__global__ void zero_ws_kernel(unsigned* __restrict__ p, int ndw) {
    int i = blockIdx.x * blockDim.x + threadIdx.x;
    int stride = gridDim.x * blockDim.x;
    for (; i < ndw; i += stride)
        __hip_atomic_store(p + i, 0u, __ATOMIC_RELAXED, SCOPE);
}

__global__ __launch_bounds__(256, 1)
void lstm_persist(const float* __restrict__ x,
                  const float* __restrict__ Wx0, const float* __restrict__ bx0,
                  const float* __restrict__ Wh0,
                  const float* __restrict__ Wx1, const float* __restrict__ bx1,
                  const float* __restrict__ Wh1,
                  const float* __restrict__ Wo,  const float* __restrict__ bo,
                  float* __restrict__ out, char* __restrict__ ws) {
    struct SM {
        float g[4][8][33];                       // gate tiles [gate][b][u0..31]+pad
        float c[8][32];                          // this WG's cell state
        float bias[4][32];                       // this WG's bias slice
        __align__(8)  f16 hout[8][32];           // activation -> packed store
        __align__(16) f16 planeA[8 * HP_STRIDE]; // h0 plane
        __align__(16) f16 planeB[8 * HP_STRIDE]; // h1 plane (L1 only)
        char  pad[60 * 1024];                    // force 1 WG/CU
    };
    __shared__ SM sm;
    __shared__ int s_fast;
    const int tid = threadIdx.x;
    if (tid == 0x00FFFFFFu) sm.pad[0] = 1;       // keep pad alive

    const int bid  = blockIdx.x;
    const int g    = bid & 7;        // group (XCD-affine under round-robin)
    const int rk   = bid >> 3;       // 0..31 within group
    const int role = rk >> 4;        // 0: layer-0 WG, 1: layer-1 WG
    const int r    = rk & 15;        // rank within role
    const int w    = tid >> 6;       // wave id = gate type (i,f,g,o)
    const int lane = tid & 63;
    const int ln   = lane & 15;
    const int q    = lane >> 4;
    const int gb8  = g * 8;

    // Flags: per-group 512 B; publisher (role,r) owns a PRIVATE 16 B slot
    // (int index r*4). Spare ints 1,2 of flag0 slot 0 hold the XCD-check
    // mask/counter (agent-scope, DEAD after init).
    int* barb  = (int*)(ws + WS_FLAG_OFF) + g * 128;
    int* flag0 = barb;
    int* flag1 = barb + 64;
    f16* H0g = (f16*)(ws + WS_H0_OFF) + g * 16384;  // 4 depth planes
    f16* H1g = (f16*)(ws + WS_H1_OFF) + g * 8192;   // 2 depth planes

    // ---- LDS init -------------------------------------------------------
    ((float*)sm.c)[tid] = 0.f;                   // 8*32 = 256 floats
    if (tid < 128) {
        int gate = tid >> 5, u = tid & 31;
        const float* bx = role ? bx1 : bx0;
        sm.bias[gate][u] = bx[(gate << 9) + (r << 5) + u];
    }

    // ---- persistent weight fragments in registers -----------------------
    f16x8 W[64];
    if (role == 0) {
#pragma unroll
        for (int tau = 0; tau < 2; ++tau) {
            const int rw = (w << 9) + (r << 5) + tau * 16 + ln;
            const float* wh0r = Wh0 + (size_t)rw * 512;
#pragma unroll
            for (int kk = 0; kk < 16; ++kk)
                W[tau * 17 + kk] = pack8(wh0r + kk * 32 + q * 8);
            const float* wx0r = Wx0 + (size_t)rw * 21;
            f16x8 f = {(_Float16)0, (_Float16)0, (_Float16)0, (_Float16)0,
                       (_Float16)0, (_Float16)0, (_Float16)0, (_Float16)0};
#pragma unroll
            for (int j = 0; j < 8; ++j) {
                int kl = q * 8 + j;
                if (kl < 21) f[j] = (f16)wx0r[kl];
            }
            W[tau * 17 + 16] = f;
        }
    } else {
#pragma unroll
        for (int tau = 0; tau < 2; ++tau) {
            const int rw = (w << 9) + (r << 5) + tau * 16 + ln;
            const float* wx1r = Wx1 + (size_t)rw * 512;
            const float* wh1r = Wh1 + (size_t)rw * 512;
#pragma unroll
            for (int kk = 0; kk < 16; ++kk)
                W[tau * 32 + kk] = pack8(wx1r + kk * 32 + q * 8);
#pragma unroll
            for (int kk = 16; kk < 32; ++kk)
                W[tau * 32 + kk] = pack8(wh1r + (kk - 16) * 32 + q * 8);
        }
    }

    // ---- XCD-affinity check (one-time, agent-scope, BOUNDED) -------------
    if (tid == 0) {
        unsigned xcc;
        asm volatile("s_getreg_b32 %0, hwreg(HW_REG_XCC_ID)" : "=s"(xcc));
        __hip_atomic_fetch_or(barb + 1, (int)(1u << (xcc & 31)),
                              __ATOMIC_RELAXED, SCOPE);
        __hip_atomic_fetch_add(barb + 2, 1, __ATOMIC_RELAXED, SCOPE);
        int cnt = 0, spins = 0;
        for (;;) {
            cnt = __hip_atomic_load(barb + 2, __ATOMIC_RELAXED, SCOPE);
            if (cnt >= 32 || spins > (1 << 18)) break;   // ~2ms bound
            __builtin_amdgcn_s_sleep(2);
            ++spins;
        }
        unsigned m = (unsigned)__hip_atomic_load(barb + 1, __ATOMIC_RELAXED, SCOPE);
        s_fast = (cnt >= 32 && __popc(m) == 1) ? 1 : 0;
    }
    __syncthreads();
    const bool fast = (s_fast != 0);

    if (role == 0) {
        // =================== layer-0 pipeline stage =======================
        long long ew = 0;                          // EWMA of blocked wait (clk)
        bool pre_ok = false;                       // tail early-poll result
        for (int t = 0; t < T_STEPS; ++t) {
            const int wr = t & 3, rd = (t + 3) & 3;
            f16x8 xf = load_xfrag(x, gb8, t, ln, q);   // prefetch before wait
            if (tid < 64 && !pre_ok) {
                long long d = wait_flags(flag0, t, flag1, t - 3, lane, ew);
                ew = ewma_upd(ew, d);
            }
            __syncthreads();                           // release waves 1-3
            stage_plane(H0g + rd * 4096, sm.planeA, tid, fast);
            __syncthreads();

            f32x4 a0 = {0, 0, 0, 0}, a1 = {0, 0, 0, 0};
#pragma unroll
            for (int kk = 0; kk < 16; ++kk) {
                f16x8 A = afrag_lds(sm.planeA, kk * 32, ln, q);
                a0 = __builtin_amdgcn_mfma_f32_16x16x32_f16(A, W[kk], a0, 0, 0, 0);
                a1 = __builtin_amdgcn_mfma_f32_16x16x32_f16(A, W[17 + kk], a1, 0, 0, 0);
            }
            a0 = __builtin_amdgcn_mfma_f32_16x16x32_f16(xf, W[16], a0, 0, 0, 0);
            a1 = __builtin_amdgcn_mfma_f32_16x16x32_f16(xf, W[33], a1, 0, 0, 0);
            if (q < 2) {
#pragma unroll
                for (int r4 = 0; r4 < 4; ++r4) {
                    sm.g[w][q * 4 + r4][ln] = a0[r4];
                    sm.g[w][q * 4 + r4][16 + ln] = a1[r4];
                }
            }
            __syncthreads();
            {   // activation: 8 batches x 32 units = 256 threads
                int b = tid >> 5, u = tid & 31;
                float gi = sm.g[0][b][u] + sm.bias[0][u];
                float gf = sm.g[1][b][u] + sm.bias[1][u];
                float gg = sm.g[2][b][u] + sm.bias[2][u];
                float go = sm.g[3][b][u] + sm.bias[3][u];
                float iv = sigm_(gi), fv = sigm_(gf), gv = tanh_(gg), ov = sigm_(go);
                float c = sm.c[b][u];
                float cn = fv * c + iv * gv;
                sm.c[b][u] = cn;
                sm.hout[b][u] = (f16)(ov * tanh_(cn));
            }
            __syncthreads();
            if (tid < 64) {   // 512 B contiguous WG slice, wave-0 only
                int b = tid >> 3, j = tid & 7;
                u64 v = *(const u64*)&sm.hout[b][j * 4];
                u64* dp = (u64*)(H0g + wr * 4096 + (r << 8) + (b << 5) + (j << 2));
                if (fast) *dp = v;                 // plain: write-through to L2
                else __hip_atomic_store(dp, v, __ATOMIC_RELAXED, SCOPE);
                asm volatile("s_waitcnt vmcnt(0)" ::: "memory");
                if (tid == 0)                       // flag ALWAYS agent-scope
                    __hip_atomic_store(flag0 + r * 4, t + 1, __ATOMIC_RELAXED, SCOPE);
                // ---- tail early-poll (retry x3) for step t+1 -------------
                pre_ok = (t + 1 < T_STEPS) &&
                         check_flags_retry(flag0, t + 1, flag1, t - 2, lane);
            }
        }
    } else {
        // =================== layer-1 pipeline stage =======================
        long long ew = 0;                          // EWMA of blocked wait (clk)
        bool pre_ok = false;                       // tail early-poll result
        for (int t = 0; t < T_STEPS; ++t) {
            const int wr = t & 1, rd = wr ^ 1;

            if (tid < 64 && !pre_ok) {
                long long d = wait_flags(flag0, t + 1, flag1, t, lane, ew);
                ew = ewma_upd(ew, d);
            }
            __syncthreads();
            stage_two(H0g + (t & 3) * 4096, sm.planeA,   // h0(t)
                      H1g + rd * 4096,      sm.planeB,   // h1(t-1)
                      tid, fast);
            __syncthreads();

            f32x4 a0 = {0, 0, 0, 0}, a1 = {0, 0, 0, 0};
#pragma unroll
            for (int kk = 0; kk < 16; ++kk) {
                f16x8 A = afrag_lds(sm.planeA, kk * 32, ln, q);
                a0 = __builtin_amdgcn_mfma_f32_16x16x32_f16(A, W[kk], a0, 0, 0, 0);
                a1 = __builtin_amdgcn_mfma_f32_16x16x32_f16(A, W[32 + kk], a1, 0, 0, 0);
            }
#pragma unroll
            for (int kk = 16; kk < 32; ++kk) {
                f16x8 A = afrag_lds(sm.planeB, (kk - 16) * 32, ln, q);
                a0 = __builtin_amdgcn_mfma_f32_16x16x32_f16(A, W[kk], a0, 0, 0, 0);
                a1 = __builtin_amdgcn_mfma_f32_16x16x32_f16(A, W[32 + kk], a1, 0, 0, 0);
            }
            if (q < 2) {
#pragma unroll
                for (int r4 = 0; r4 < 4; ++r4) {
                    sm.g[w][q * 4 + r4][ln] = a0[r4];
                    sm.g[w][q * 4 + r4][16 + ln] = a1[r4];
                }
            }
            __syncthreads();
            {
                int b = tid >> 5, u = tid & 31;
                float gi = sm.g[0][b][u] + sm.bias[0][u];
                float gf = sm.g[1][b][u] + sm.bias[1][u];
                float gg = sm.g[2][b][u] + sm.bias[2][u];
                float go = sm.g[3][b][u] + sm.bias[3][u];
                float iv = sigm_(gi), fv = sigm_(gf), gv = tanh_(gg), ov = sigm_(go);
                float c = sm.c[b][u];
                float cn = fv * c + iv * gv;
                sm.c[b][u] = cn;
                sm.hout[b][u] = (f16)(ov * tanh_(cn));
            }
            __syncthreads();
            if (tid < 64) {
                int b = tid >> 3, j = tid & 7;
                u64 v = *(const u64*)&sm.hout[b][j * 4];
                u64* dp = (u64*)(H1g + wr * 4096 + (r << 8) + (b << 5) + (j << 2));
                if (fast) *dp = v;
                else __hip_atomic_store(dp, v, __ATOMIC_RELAXED, SCOPE);
                asm volatile("s_waitcnt vmcnt(0)" ::: "memory");
                if (tid == 0)
                    __hip_atomic_store(flag1 + r * 4, t + 1, __ATOMIC_RELAXED, SCOPE);
            }

            // ---- out-proj(t-1) AFTER publish, from LDS planeB (off the
            // inter-WG path). Safe: planeB's next overwrite is after the next
            // head wait's __syncthreads, which orders it after these reads.
            if (t > 0) {
                int p = tid >> 4, kp = tid & 15;
                int valid = (p < 10);
                int idx = r * 10 + p;
                int b = valid ? idx / 20 : 0, o = valid ? idx % 20 : 0;
                float a = 0.f;
                if (valid) {
                    const f16* hp = sm.planeB + b * HP_STRIDE + kp * 32;
                    const float* wo = Wo + (size_t)o * 512 + kp * 32;
#pragma unroll
                    for (int k = 0; k < 32; k += 8) {
                        f16x8 hv = *(const f16x8*)(hp + k);
                        float4 wa = *(const float4*)(wo + k);
                        float4 wb = *(const float4*)(wo + k + 4);
                        a += (float)hv[0] * wa.x + (float)hv[1] * wa.y +
                             (float)hv[2] * wa.z + (float)hv[3] * wa.w +
                             (float)hv[4] * wb.x + (float)hv[5] * wb.y +
                             (float)hv[6] * wb.z + (float)hv[7] * wb.w;
                    }
                }
                a += __shfl_down(a, 8, 16);
                a += __shfl_down(a, 4, 16);
                a += __shfl_down(a, 2, 16);
                a += __shfl_down(a, 1, 16);
                if (valid && kp == 0)
                    out[((size_t)(gb8 + b) * 1024 + (t - 1)) * 20 + o] =
                        sigm_(a + bo[o]);
            }

            // ---- tail early-poll (retry x3) for step t+1 -----------------
            if (tid < 64)
                pre_ok = (t + 1 < T_STEPS) &&
                         check_flags_retry(flag0, t + 2, flag1, t + 1, lane);
        }

        // ===== epilogue: out(T-1) from h1(T-1) =============================
        if (tid < 64) wait_flags(flag1, T_STEPS, flag1, T_STEPS, lane, 0);
        __syncthreads();
        stage_plane(H1g + ((T_STEPS - 1) & 1) * 4096, sm.planeB, tid, fast);
        __syncthreads();
        {
            int p = tid >> 4, kp = tid & 15;
            int valid = (p < 10);
            int idx = r * 10 + p;
            int b = valid ? idx / 20 : 0, o = valid ? idx % 20 : 0;
            float a = 0.f;
            if (valid) {
                const f16* hp = sm.planeB + b * HP_STRIDE + kp * 32;
                const float* wo = Wo + (size_t)o * 512 + kp * 32;
#pragma unroll
                for (int k = 0; k < 32; k += 8) {
                    f16x8 hv = *(const f16x8*)(hp + k);
                    float4 wa = *(const float4*)(wo + k);
                    float4 wb = *(const float4*)(wo + k + 4);
                    a += (float)hv[0] * wa.x + (float)hv[1] * wa.y +
                         (float)hv[2] * wa.z + (float)hv[3] * wa.w +
                         (float)hv[4] * wb.x + (float)hv[5] * wb.y +
                         (float)hv[6] * wb.z + (float)hv[7] * wb.w;
                }
            }
            a += __shfl_down(a, 8, 16);
            a += __shfl_down(a, 4, 16);
            a += __shfl_down(a, 2, 16);
            a += __shfl_down(a, 1, 16);
            if (valid && kp == 0)
                out[((size_t)(gb8 + b) * 1024 + (T_STEPS - 1)) * 20 + o] =
                    sigm_(a + bo[o]);
        }
    }
}

extern "C" void kernel_launch(void* const* d_in, const int* in_sizes, int n_in,
                              void* d_out, int out_size, void* d_ws, size_t ws_size,
                              hipStream_t stream) {
    const float* x   = (const float*)d_in[0];
    const float* Wx0 = (const float*)d_in[1];
    const float* bx0 = (const float*)d_in[2];
    const float* Wh0 = (const float*)d_in[3];
    const float* Wx1 = (const float*)d_in[4];
    const float* bx1 = (const float*)d_in[5];
    const float* Wh1 = (const float*)d_in[6];
    const float* Wo  = (const float*)d_in[7];
    const float* bo  = (const float*)d_in[8];
    float* out = (float*)d_out;
    char*  ws  = (char*)d_ws;

    if (ws_size < (size_t)WS_NEED) return;   // fail visibly (out stays poisoned)

    zero_ws_kernel<<<128, 256, 0, stream>>>((unsigned*)ws, WS_NEED / 4);
    lstm_persist<<<256, 256, 0, stream>>>(x, Wx0, bx0, Wh0, Wx1, bx1, Wh1,
                                          Wo, bo, out, ws);
}

// Round 15
// 3258.255 us; speedup vs baseline: 1.0507x; 1.0507x over previous
//
#include <hip/hip_runtime.h>

// ---------------------------------------------------------------------------
// Persistent 2-layer LSTM, MI355X. Round 26 = REVERT to Round-24 (3269 us,
// session best). r25 post-mortem: bounded tail-retry REGRESSED (+8%, outlier
// returned) — tail retries add serial time to wave0's path even when flags
// would be head-visible anyway, and the extra poll traffic at the publish
// instant re-pressured the flag lines. Poll-tuning is now exhausted:
// r15 neutral, r24 +5% (single tail check), r25 negative (retry x3).
// Lever ledger (proven wins kept): merged L1 wait+dual-stage (r13), private
// 16B flag slots + branchless afrag (r18), XCD-verified L2 data path (r20),
// single tail early-poll (r24). Proven dead ends: fast flags (r19/r21 hang
// 2/2), 512-thread WGs (r16 spill), tighter inter-WG gates (r22), work
// redistribution (r23 neutral), retry depth (r25).
// ---------------------------------------------------------------------------

#define T_STEPS 1024
#define WS_FLAG_OFF 0                     // 8 groups * 512 B: 32 pubs x 16 B each
#define WS_H0_OFF  4096                   // [8 g][4 depth][16 wg][8 b][32 u] f16
#define WS_H1_OFF  (4096 + 8*4*8192)      // [8 g][2 depth][...]
#define WS_NEED    (WS_H1_OFF + 8*2*8192) // 397312 B (known-good size)

#define SCOPE __HIP_MEMORY_SCOPE_AGENT

typedef _Float16 f16;
typedef _Float16 f16x8 __attribute__((ext_vector_type(8)));
typedef float    f32x4 __attribute__((ext_vector_type(4)));
typedef unsigned long long u64;

#define HP_STRIDE 520   // padded LDS plane row stride (f16)

__device__ __forceinline__ float sigm_(float x) {
    x = fminf(fmaxf(x, -30.f), 30.f);
    return 1.f / (1.f + __expf(-x));
}
__device__ __forceinline__ float tanh_(float x) {
    x = fminf(fmaxf(x, -15.f), 15.f);
    float e = __expf(-2.f * x);
    return (1.f - e) / (1.f + e);
}

// A-fragment for 16x16x32 f16 MFMA from a padded LDS plane — BRANCHLESS
// (r18): lanes 8-15 re-read rows 0-7; their D rows are discarded by the q<2
// store guard.
__device__ __forceinline__ f16x8 afrag_lds(const f16* __restrict__ hp, int kbase,
                                           int b, int q) {
    return *(const f16x8*)(hp + (b & 7) * HP_STRIDE + kbase + q * 8);
}

__device__ __forceinline__ f16x8 pack8(const float* p) {
    float4 a = *(const float4*)p, b = *(const float4*)(p + 4);
    f16x8 f;
    f[0] = (f16)a.x; f[1] = (f16)a.y; f[2] = (f16)a.z; f[3] = (f16)a.w;
    f[4] = (f16)b.x; f[5] = (f16)b.y; f[6] = (f16)b.z; f[7] = (f16)b.w;
    return f;
}

// One-shot NON-BLOCKING flag check (wave0 only; lanes 0-15 flag0, 16-31
// flag1, 32-63 INT_MAX). Flags are monotone, so a pass observed in the tail
// remains valid at the next head. SINGLE check only (r25: retries regress).
__device__ __forceinline__ bool check_flags(const int* f0, int t0,
                                            const int* f1, int t1, int lane) {
    const int* p = (lane & 16) ? (f1 + (lane & 15) * 4) : (f0 + (lane & 15) * 4);
    const int tgt = (lane & 16) ? t1 : t0;
    const bool act = (lane < 32);
    int v = act ? __hip_atomic_load(p, __ATOMIC_RELAXED, SCOPE) : 0x7fffffff;
    return __all(v >= tgt);
}

// Blocking wait (r15/r18): EWMA predictive coarse sleep then fine-poll.
// ALWAYS agent-scope (r19/r21 lesson: fast flags hang, 2/2).
__device__ __forceinline__ long long wait_flags(const int* f0, int t0,
                                                const int* f1, int t1, int lane,
                                                long long predict_clk) {
    const int* p = (lane & 16) ? (f1 + (lane & 15) * 4) : (f0 + (lane & 15) * 4);
    const int tgt = (lane & 16) ? t1 : t0;
    const bool act = (lane < 32);
    int v = act ? __hip_atomic_load(p, __ATOMIC_RELAXED, SCOPE) : 0x7fffffff;
    if (__all(v >= tgt)) return 0;                 // fast path: no wait
    long long t0c = (long long)__builtin_amdgcn_s_memtime();
    int rep = (int)(predict_clk >> 12);            // ~half wait / ~2000cy burst
    if (rep > 8) rep = 8;
    for (int i = 0; i < rep; ++i) __builtin_amdgcn_s_sleep(31);
    int spins = 0;
    for (;;) {
        v = act ? __hip_atomic_load(p, __ATOMIC_RELAXED, SCOPE) : 0x7fffffff;
        if (__all(v >= tgt)) break;
        ++spins;
        if (spins < 32)       __builtin_amdgcn_s_sleep(1);
        else if (spins < 256) __builtin_amdgcn_s_sleep(4);
        else                  __builtin_amdgcn_s_sleep(16);
        if (spins > (1 << 20)) break;   // anti-hang safety valve
    }
    return (long long)__builtin_amdgcn_s_memtime() - t0c;
}

// EWMA update: decay toward the new sample (or toward 0 on fast path).
__device__ __forceinline__ long long ewma_upd(long long ew, long long d) {
    return ew - (ew >> 2) + (d >> 2);
}

// sc0 (L1-bypass, L2-served) u64 load for the XCD-local fast path.
__device__ __forceinline__ u64 ld8_sc0(const u64* p) {
    u64 v;
    asm volatile("global_load_dwordx2 %0, %1, off sc0" : "=v"(v) : "v"(p));
    return v;
}

// Stage one 8 KB h-plane into the padded LDS plane.
__device__ __forceinline__ void stage_plane(const f16* __restrict__ gp,
                                            f16* __restrict__ dst, int tid,
                                            bool fast) {
    const u64* g8 = (const u64*)gp;
    u64 v[4];
    if (fast) {
#pragma unroll
        for (int jj = 0; jj < 4; ++jj) v[jj] = ld8_sc0(g8 + jj * 256 + tid);
        asm volatile("s_waitcnt vmcnt(0)" ::: "memory");
    } else {
#pragma unroll
        for (int jj = 0; jj < 4; ++jj)
            v[jj] = __hip_atomic_load(g8 + jj * 256 + tid, __ATOMIC_RELAXED, SCOPE);
    }
#pragma unroll
    for (int jj = 0; jj < 4; ++jj) {
        int i = jj * 256 + tid;
        int wg = i >> 6, b = (i >> 3) & 7, j = i & 7;
        *(u64*)(dst + b * HP_STRIDE + wg * 32 + j * 4) = v[jj];
    }
}

// Stage TWO 8 KB h-planes in one pass (one RT on the serial chain, r13).
__device__ __forceinline__ void stage_two(const f16* __restrict__ gpA,
                                          f16* __restrict__ dstA,
                                          const f16* __restrict__ gpB,
                                          f16* __restrict__ dstB, int tid,
                                          bool fast) {
    const u64* ga = (const u64*)gpA;
    const u64* gb = (const u64*)gpB;
    u64 va[4], vb[4];
    if (fast) {
#pragma unroll
        for (int jj = 0; jj < 4; ++jj) va[jj] = ld8_sc0(ga + jj * 256 + tid);
#pragma unroll
        for (int jj = 0; jj < 4; ++jj) vb[jj] = ld8_sc0(gb + jj * 256 + tid);
        asm volatile("s_waitcnt vmcnt(0)" ::: "memory");
    } else {
#pragma unroll
        for (int jj = 0; jj < 4; ++jj)
            va[jj] = __hip_atomic_load(ga + jj * 256 + tid, __ATOMIC_RELAXED, SCOPE);
#pragma unroll
        for (int jj = 0; jj < 4; ++jj)
            vb[jj] = __hip_atomic_load(gb + jj * 256 + tid, __ATOMIC_RELAXED, SCOPE);
    }
#pragma unroll
    for (int jj = 0; jj < 4; ++jj) {
        int i = jj * 256 + tid;
        int wg = i >> 6, b = (i >> 3) & 7, j = i & 7;
        *(u64*)(dstA + b * HP_STRIDE + wg * 32 + j * 4) = va[jj];
        *(u64*)(dstB + b * HP_STRIDE + wg * 32 + j * 4) = vb[jj];
    }
}

// x A-fragment for step t.
__device__ __forceinline__ f16x8 load_xfrag(const float* __restrict__ x,
                                            int gb8, int t, int ln, int q) {
    f16x8 f = {(_Float16)0, (_Float16)0, (_Float16)0, (_Float16)0,
               (_Float16)0, (_Float16)0, (_Float16)0, (_Float16)0};
    if (ln < 8 && t < T_STEPS) {
        const float* xp = x + ((size_t)(gb8 + ln) * 1024 + t) * 21;
#pragma unroll
        for (int j = 0; j < 8; ++j) {
            int kl = q * 8 + j;
            if (kl < 21) f[j] = (f16)xp[kl];
        }
    }
    return f;
}

// Zeros visible everywhere: agent-scope stores invalidate stale dirty L2
// lines (r20-proven across 68 dispatches) and land in the LLC.
__global__ void zero_ws_kernel(unsigned* __restrict__ p, int ndw) {
    int i = blockIdx.x * blockDim.x + threadIdx.x;
    int stride = gridDim.x * blockDim.x;
    for (; i < ndw; i += stride)
        __hip_atomic_store(p + i, 0u, __ATOMIC_RELAXED, SCOPE);
}

__global__ __launch_bounds__(256, 1)
void lstm_persist(const float* __restrict__ x,
                  const float* __restrict__ Wx0, const float* __restrict__ bx0,
                  const float* __restrict__ Wh0,
                  const float* __restrict__ Wx1, const float* __restrict__ bx1,
                  const float* __restrict__ Wh1,
                  const float* __restrict__ Wo,  const float* __restrict__ bo,
                  float* __restrict__ out, char* __restrict__ ws) {
    struct SM {
        float g[4][8][33];                       // gate tiles [gate][b][u0..31]+pad
        float c[8][32];                          // this WG's cell state
        float bias[4][32];                       // this WG's bias slice
        __align__(8)  f16 hout[8][32];           // activation -> packed store
        __align__(16) f16 planeA[8 * HP_STRIDE]; // h0 plane
        __align__(16) f16 planeB[8 * HP_STRIDE]; // h1 plane (L1 only)
        char  pad[60 * 1024];                    // force 1 WG/CU
    };
    __shared__ SM sm;
    __shared__ int s_fast;
    const int tid = threadIdx.x;
    if (tid == 0x00FFFFFFu) sm.pad[0] = 1;       // keep pad alive

    const int bid  = blockIdx.x;
    const int g    = bid & 7;        // group (XCD-affine under round-robin)
    const int rk   = bid >> 3;       // 0..31 within group
    const int role = rk >> 4;        // 0: layer-0 WG, 1: layer-1 WG
    const int r    = rk & 15;        // rank within role
    const int w    = tid >> 6;       // wave id = gate type (i,f,g,o)
    const int lane = tid & 63;
    const int ln   = lane & 15;
    const int q    = lane >> 4;
    const int gb8  = g * 8;

    // Flags: per-group 512 B; publisher (role,r) owns a PRIVATE 16 B slot
    // (int index r*4). Spare ints 1,2 of flag0 slot 0 hold the XCD-check
    // mask/counter (agent-scope, DEAD after init).
    int* barb  = (int*)(ws + WS_FLAG_OFF) + g * 128;
    int* flag0 = barb;
    int* flag1 = barb + 64;
    f16* H0g = (f16*)(ws + WS_H0_OFF) + g * 16384;  // 4 depth planes
    f16* H1g = (f16*)(ws + WS_H1_OFF) + g * 8192;   // 2 depth planes

    // ---- LDS init -------------------------------------------------------
    ((float*)sm.c)[tid] = 0.f;                   // 8*32 = 256 floats
    if (tid < 128) {
        int gate = tid >> 5, u = tid & 31;
        const float* bx = role ? bx1 : bx0;
        sm.bias[gate][u] = bx[(gate << 9) + (r << 5) + u];
    }

    // ---- persistent weight fragments in registers -----------------------
    f16x8 W[64];
    if (role == 0) {
#pragma unroll
        for (int tau = 0; tau < 2; ++tau) {
            const int rw = (w << 9) + (r << 5) + tau * 16 + ln;
            const float* wh0r = Wh0 + (size_t)rw * 512;
#pragma unroll
            for (int kk = 0; kk < 16; ++kk)
                W[tau * 17 + kk] = pack8(wh0r + kk * 32 + q * 8);
            const float* wx0r = Wx0 + (size_t)rw * 21;
            f16x8 f = {(_Float16)0, (_Float16)0, (_Float16)0, (_Float16)0,
                       (_Float16)0, (_Float16)0, (_Float16)0, (_Float16)0};
#pragma unroll
            for (int j = 0; j < 8; ++j) {
                int kl = q * 8 + j;
                if (kl < 21) f[j] = (f16)wx0r[kl];
            }
            W[tau * 17 + 16] = f;
        }
    } else {
#pragma unroll
        for (int tau = 0; tau < 2; ++tau) {
            const int rw = (w << 9) + (r << 5) + tau * 16 + ln;
            const float* wx1r = Wx1 + (size_t)rw * 512;
            const float* wh1r = Wh1 + (size_t)rw * 512;
#pragma unroll
            for (int kk = 0; kk < 16; ++kk)
                W[tau * 32 + kk] = pack8(wx1r + kk * 32 + q * 8);
#pragma unroll
            for (int kk = 16; kk < 32; ++kk)
                W[tau * 32 + kk] = pack8(wh1r + (kk - 16) * 32 + q * 8);
        }
    }

    // ---- XCD-affinity check (one-time, agent-scope, BOUNDED) -------------
    if (tid == 0) {
        unsigned xcc;
        asm volatile("s_getreg_b32 %0, hwreg(HW_REG_XCC_ID)" : "=s"(xcc));
        __hip_atomic_fetch_or(barb + 1, (int)(1u << (xcc & 31)),
                              __ATOMIC_RELAXED, SCOPE);
        __hip_atomic_fetch_add(barb + 2, 1, __ATOMIC_RELAXED, SCOPE);
        int cnt = 0, spins = 0;
        for (;;) {
            cnt = __hip_atomic_load(barb + 2, __ATOMIC_RELAXED, SCOPE);
            if (cnt >= 32 || spins > (1 << 18)) break;   // ~2ms bound
            __builtin_amdgcn_s_sleep(2);
            ++spins;
        }
        unsigned m = (unsigned)__hip_atomic_load(barb + 1, __ATOMIC_RELAXED, SCOPE);
        s_fast = (cnt >= 32 && __popc(m) == 1) ? 1 : 0;
    }
    __syncthreads();
    const bool fast = (s_fast != 0);

    if (role == 0) {
        // =================== layer-0 pipeline stage =======================
        long long ew = 0;                          // EWMA of blocked wait (clk)
        bool pre_ok = false;                       // tail early-poll result
        for (int t = 0; t < T_STEPS; ++t) {
            const int wr = t & 3, rd = (t + 3) & 3;
            f16x8 xf = load_xfrag(x, gb8, t, ln, q);   // prefetch before wait
            if (tid < 64 && !pre_ok) {
                long long d = wait_flags(flag0, t, flag1, t - 3, lane, ew);
                ew = ewma_upd(ew, d);
            }
            __syncthreads();                           // release waves 1-3
            stage_plane(H0g + rd * 4096, sm.planeA, tid, fast);
            __syncthreads();

            f32x4 a0 = {0, 0, 0, 0}, a1 = {0, 0, 0, 0};
#pragma unroll
            for (int kk = 0; kk < 16; ++kk) {
                f16x8 A = afrag_lds(sm.planeA, kk * 32, ln, q);
                a0 = __builtin_amdgcn_mfma_f32_16x16x32_f16(A, W[kk], a0, 0, 0, 0);
                a1 = __builtin_amdgcn_mfma_f32_16x16x32_f16(A, W[17 + kk], a1, 0, 0, 0);
            }
            a0 = __builtin_amdgcn_mfma_f32_16x16x32_f16(xf, W[16], a0, 0, 0, 0);
            a1 = __builtin_amdgcn_mfma_f32_16x16x32_f16(xf, W[33], a1, 0, 0, 0);
            if (q < 2) {
#pragma unroll
                for (int r4 = 0; r4 < 4; ++r4) {
                    sm.g[w][q * 4 + r4][ln] = a0[r4];
                    sm.g[w][q * 4 + r4][16 + ln] = a1[r4];
                }
            }
            __syncthreads();
            {   // activation: 8 batches x 32 units = 256 threads
                int b = tid >> 5, u = tid & 31;
                float gi = sm.g[0][b][u] + sm.bias[0][u];
                float gf = sm.g[1][b][u] + sm.bias[1][u];
                float gg = sm.g[2][b][u] + sm.bias[2][u];
                float go = sm.g[3][b][u] + sm.bias[3][u];
                float iv = sigm_(gi), fv = sigm_(gf), gv = tanh_(gg), ov = sigm_(go);
                float c = sm.c[b][u];
                float cn = fv * c + iv * gv;
                sm.c[b][u] = cn;
                sm.hout[b][u] = (f16)(ov * tanh_(cn));
            }
            __syncthreads();
            if (tid < 64) {   // 512 B contiguous WG slice, wave-0 only
                int b = tid >> 3, j = tid & 7;
                u64 v = *(const u64*)&sm.hout[b][j * 4];
                u64* dp = (u64*)(H0g + wr * 4096 + (r << 8) + (b << 5) + (j << 2));
                if (fast) *dp = v;                 // plain: write-through to L2
                else __hip_atomic_store(dp, v, __ATOMIC_RELAXED, SCOPE);
                asm volatile("s_waitcnt vmcnt(0)" ::: "memory");
                if (tid == 0)                       // flag ALWAYS agent-scope
                    __hip_atomic_store(flag0 + r * 4, t + 1, __ATOMIC_RELAXED, SCOPE);
                // ---- tail early-poll for step t+1 (off critical path) ----
                pre_ok = (t + 1 < T_STEPS) &&
                         check_flags(flag0, t + 1, flag1, t - 2, lane);
            }
        }
    } else {
        // =================== layer-1 pipeline stage =======================
        long long ew = 0;                          // EWMA of blocked wait (clk)
        bool pre_ok = false;                       // tail early-poll result
        for (int t = 0; t < T_STEPS; ++t) {
            const int wr = t & 1, rd = wr ^ 1;

            if (tid < 64 && !pre_ok) {
                long long d = wait_flags(flag0, t + 1, flag1, t, lane, ew);
                ew = ewma_upd(ew, d);
            }
            __syncthreads();
            stage_two(H0g + (t & 3) * 4096, sm.planeA,   // h0(t)
                      H1g + rd * 4096,      sm.planeB,   // h1(t-1)
                      tid, fast);
            __syncthreads();

            f32x4 a0 = {0, 0, 0, 0}, a1 = {0, 0, 0, 0};
#pragma unroll
            for (int kk = 0; kk < 16; ++kk) {
                f16x8 A = afrag_lds(sm.planeA, kk * 32, ln, q);
                a0 = __builtin_amdgcn_mfma_f32_16x16x32_f16(A, W[kk], a0, 0, 0, 0);
                a1 = __builtin_amdgcn_mfma_f32_16x16x32_f16(A, W[32 + kk], a1, 0, 0, 0);
            }
#pragma unroll
            for (int kk = 16; kk < 32; ++kk) {
                f16x8 A = afrag_lds(sm.planeB, (kk - 16) * 32, ln, q);
                a0 = __builtin_amdgcn_mfma_f32_16x16x32_f16(A, W[kk], a0, 0, 0, 0);
                a1 = __builtin_amdgcn_mfma_f32_16x16x32_f16(A, W[32 + kk], a1, 0, 0, 0);
            }
            if (q < 2) {
#pragma unroll
                for (int r4 = 0; r4 < 4; ++r4) {
                    sm.g[w][q * 4 + r4][ln] = a0[r4];
                    sm.g[w][q * 4 + r4][16 + ln] = a1[r4];
                }
            }
            __syncthreads();
            {
                int b = tid >> 5, u = tid & 31;
                float gi = sm.g[0][b][u] + sm.bias[0][u];
                float gf = sm.g[1][b][u] + sm.bias[1][u];
                float gg = sm.g[2][b][u] + sm.bias[2][u];
                float go = sm.g[3][b][u] + sm.bias[3][u];
                float iv = sigm_(gi), fv = sigm_(gf), gv = tanh_(gg), ov = sigm_(go);
                float c = sm.c[b][u];
                float cn = fv * c + iv * gv;
                sm.c[b][u] = cn;
                sm.hout[b][u] = (f16)(ov * tanh_(cn));
            }
            __syncthreads();
            if (tid < 64) {
                int b = tid >> 3, j = tid & 7;
                u64 v = *(const u64*)&sm.hout[b][j * 4];
                u64* dp = (u64*)(H1g + wr * 4096 + (r << 8) + (b << 5) + (j << 2));
                if (fast) *dp = v;
                else __hip_atomic_store(dp, v, __ATOMIC_RELAXED, SCOPE);
                asm volatile("s_waitcnt vmcnt(0)" ::: "memory");
                if (tid == 0)
                    __hip_atomic_store(flag1 + r * 4, t + 1, __ATOMIC_RELAXED, SCOPE);
            }

            // ---- out-proj(t-1) AFTER publish, from LDS planeB (off the
            // inter-WG path). Safe: planeB's next overwrite is after the next
            // head wait's __syncthreads, which orders it after these reads.
            if (t > 0) {
                int p = tid >> 4, kp = tid & 15;
                int valid = (p < 10);
                int idx = r * 10 + p;
                int b = valid ? idx / 20 : 0, o = valid ? idx % 20 : 0;
                float a = 0.f;
                if (valid) {
                    const f16* hp = sm.planeB + b * HP_STRIDE + kp * 32;
                    const float* wo = Wo + (size_t)o * 512 + kp * 32;
#pragma unroll
                    for (int k = 0; k < 32; k += 8) {
                        f16x8 hv = *(const f16x8*)(hp + k);
                        float4 wa = *(const float4*)(wo + k);
                        float4 wb = *(const float4*)(wo + k + 4);
                        a += (float)hv[0] * wa.x + (float)hv[1] * wa.y +
                             (float)hv[2] * wa.z + (float)hv[3] * wa.w +
                             (float)hv[4] * wb.x + (float)hv[5] * wb.y +
                             (float)hv[6] * wb.z + (float)hv[7] * wb.w;
                    }
                }
                a += __shfl_down(a, 8, 16);
                a += __shfl_down(a, 4, 16);
                a += __shfl_down(a, 2, 16);
                a += __shfl_down(a, 1, 16);
                if (valid && kp == 0)
                    out[((size_t)(gb8 + b) * 1024 + (t - 1)) * 20 + o] =
                        sigm_(a + bo[o]);
            }

            // ---- tail early-poll for step t+1 (hidden under out-proj) ----
            if (tid < 64)
                pre_ok = (t + 1 < T_STEPS) &&
                         check_flags(flag0, t + 2, flag1, t + 1, lane);
        }

        // ===== epilogue: out(T-1) from h1(T-1) =============================
        if (tid < 64) wait_flags(flag1, T_STEPS, flag1, T_STEPS, lane, 0);
        __syncthreads();
        stage_plane(H1g + ((T_STEPS - 1) & 1) * 4096, sm.planeB, tid, fast);
        __syncthreads();
        {
            int p = tid >> 4, kp = tid & 15;
            int valid = (p < 10);
            int idx = r * 10 + p;
            int b = valid ? idx / 20 : 0, o = valid ? idx % 20 : 0;
            float a = 0.f;
            if (valid) {
                const f16* hp = sm.planeB + b * HP_STRIDE + kp * 32;
                const float* wo = Wo + (size_t)o * 512 + kp * 32;
#pragma unroll
                for (int k = 0; k < 32; k += 8) {
                    f16x8 hv = *(const f16x8*)(hp + k);
                    float4 wa = *(const float4*)(wo + k);
                    float4 wb = *(const float4*)(wo + k + 4);
                    a += (float)hv[0] * wa.x + (float)hv[1] * wa.y +
                         (float)hv[2] * wa.z + (float)hv[3] * wa.w +
                         (float)hv[4] * wb.x + (float)hv[5] * wb.y +
                         (float)hv[6] * wb.z + (float)hv[7] * wb.w;
                }
            }
            a += __shfl_down(a, 8, 16);
            a += __shfl_down(a, 4, 16);
            a += __shfl_down(a, 2, 16);
            a += __shfl_down(a, 1, 16);
            if (valid && kp == 0)
                out[((size_t)(gb8 + b) * 1024 + (T_STEPS - 1)) * 20 + o] =
                    sigm_(a + bo[o]);
        }
    }
}

extern "C" void kernel_launch(void* const* d_in, const int* in_sizes, int n_in,
                              void* d_out, int out_size, void* d_ws, size_t ws_size,
                              hipStream_t stream) {
    const float* x   = (const float*)d_in[0];
    const float* Wx0 = (const float*)d_in[1];
    const float* bx0 = (const float*)d_in[2];
    const float* Wh0 = (const float*)d_in[3];
    const float* Wx1 = (const float*)d_in[4];
    const float* bx1 = (const float*)d_in[5];
    const float* Wh1 = (const float*)d_in[6];
    const float* Wo  = (const float*)d_in[7];
    const float* bo  = (const float*)d_in[8];
    float* out = (float*)d_out;
    char*  ws  = (char*)d_ws;

    if (ws_size < (size_t)WS_NEED) return;   // fail visibly (out stays poisoned)

    zero_ws_kernel<<<128, 256, 0, stream>>>((unsigned*)ws, WS_NEED / 4);
    lstm_persist<<<256, 256, 0, stream>>>(x, Wx0, bx0, Wh0, Wx1, bx1, Wh1,
                                          Wo, bo, out, ws);
}